// Round 16
// baseline (375.633 us; speedup 1.0000x reference)
//
#include <hip/hip_runtime.h>

#define KOFF 27
#define MPAIR 100000
#define NPAIR (KOFF * MPAIR)        // 2,700,000
#define NIN 200000
#define NOUT 400000
#define CIN 32
#define COUT 32

#define ROWS_PER_BIN 256
#define NBIN 1563                   // out bins = ceil(400000/256)
#define CAPB 3072                   // LDS sort-chunk capacity
#define BPB 8192
#define CHROWS 1024
#define NCHUNK 196                  // ceil(200000/1024)
#define NBINC (KOFF * NCHUNK)       // 5292 (k,chunk) in-bins

// ---------- workspace layout (bytes) ----------
#define O_CNTI   ((size_t)8192)       // 5292*4
#define O_CNTO   ((size_t)32768)      // 1563*4
#define O_BASI   ((size_t)40960)      // 5293*4
#define O_BASO   ((size_t)65536)      // 1564*4
#define O_CURI   ((size_t)73728)      // 5292*4
#define O_CURO   ((size_t)98304)      // 1563*4
#define O_BINI   ((size_t)106496)     // 2.7M*4  = 10,800,000 -> 10,906,496
#define O_BINO   ((size_t)10906496)   // 2.7M*1  =  2,700,000 -> 13,606,496
#define O_PEROFF ((size_t)13606528)   // 2.7M*64 = 172,800,000 -> 186,406,528
#define O_F16    ((size_t)186406528)  // 12,800,000 -> 199,206,528
#define WS_NEED  ((size_t)199206528)

typedef unsigned int uint4n __attribute__((ext_vector_type(4)));

__device__ __forceinline__ unsigned int bf16pair(float a, float b) {
    unsigned int ua = __float_as_uint(a), ub = __float_as_uint(b);
    ua = (ua + 0x7fffu + ((ua >> 16) & 1u)) >> 16;   // RNE
    ub = (ub + 0x7fffu + ((ub >> 16) & 1u)) >> 16;
    return ua | (ub << 16);
}
__device__ __forceinline__ float bf2f(unsigned short v) {
    return __uint_as_float(((unsigned int)v) << 16);
}
__device__ __forceinline__ float bf2f_lo(unsigned int w) {
    return __uint_as_float(w << 16);
}
__device__ __forceinline__ float bf2f_hi(unsigned int w) {
    return __uint_as_float(w & 0xFFFF0000u);
}

// ---------- Phase 0: feats f32 -> bf16 ----------
__global__ __launch_bounds__(256) void cvt_kernel(
    const float* __restrict__ feats, unsigned short* __restrict__ f16)
{
    int i = blockIdx.x * 256 + threadIdx.x;
    if (i >= NIN * CIN / 8) return;
    const float4* src = reinterpret_cast<const float4*>(feats) + i * 2;
    float4 a = src[0], b = src[1];
    uint4n u;
    u.x = bf16pair(a.x, a.y); u.y = bf16pair(a.z, a.w);
    u.z = bf16pair(b.x, b.y); u.w = bf16pair(b.z, b.w);
    reinterpret_cast<uint4n*>(f16)[i] = u;
}

// ---------- Phase 1: dual histogram (in: k,chunk | out: row-bin) ----------
__global__ __launch_bounds__(256) void hist2_kernel(
    const int* __restrict__ in_map, const int* __restrict__ out_map,
    int* __restrict__ cnt_in, int* __restrict__ cnt_out)
{
    __shared__ int hi[NBINC];        // 21.2 KB
    __shared__ int ho[NBIN];         // 6.3 KB
    const int t = threadIdx.x;
    const int base = blockIdx.x * BPB;
    for (int c = t; c < NBINC; c += 256) hi[c] = 0;
    for (int c = t; c < NBIN; c += 256) ho[c] = 0;
    __syncthreads();
    for (int i = t; i < BPB; i += 256) {
        int p = base + i;
        if (p < NPAIR) {
            atomicAdd(&hi[(p / MPAIR) * NCHUNK + (in_map[p] >> 10)], 1);
            atomicAdd(&ho[out_map[p] >> 8], 1);
        }
    }
    __syncthreads();
    for (int c = t; c < NBINC; c += 256) if (hi[c]) atomicAdd(&cnt_in[c], hi[c]);
    for (int c = t; c < NBIN; c += 256) if (ho[c]) atomicAdd(&cnt_out[c], ho[c]);
}

// ---------- Phase 2: exclusive scans (both arrays, one block) ----------
__global__ __launch_bounds__(256) void scan2_kernel(
    const int* __restrict__ cnt_in, const int* __restrict__ cnt_out,
    int* __restrict__ bas_in, int* __restrict__ bas_out,
    int* __restrict__ cur_in, int* __restrict__ cur_out)
{
    __shared__ int lsum[256];
    const int t = threadIdx.x;
    {   // in-bins: 21/thread
        int v[21]; int s = 0;
#pragma unroll
        for (int j = 0; j < 21; ++j) {
            int i = t * 21 + j;
            v[j] = (i < NBINC) ? cnt_in[i] : 0;
            s += v[j];
        }
        lsum[t] = s;
        __syncthreads();
        for (int off = 1; off < 256; off <<= 1) {
            int w = (t >= off) ? lsum[t - off] : 0;
            __syncthreads();
            lsum[t] += w;
            __syncthreads();
        }
        int run = lsum[t] - s;
#pragma unroll
        for (int j = 0; j < 21; ++j) {
            int i = t * 21 + j;
            if (i < NBINC) { bas_in[i] = run; cur_in[i] = run; run += v[j]; }
        }
        if (t == 255) bas_in[NBINC] = run;
        __syncthreads();
    }
    {   // out-bins: 7/thread
        int v[7]; int s = 0;
#pragma unroll
        for (int j = 0; j < 7; ++j) {
            int i = t * 7 + j;
            v[j] = (i < NBIN) ? cnt_out[i] : 0;
            s += v[j];
        }
        lsum[t] = s;
        __syncthreads();
        for (int off = 1; off < 256; off <<= 1) {
            int w = (t >= off) ? lsum[t - off] : 0;
            __syncthreads();
            lsum[t] += w;
            __syncthreads();
        }
        int run = lsum[t] - s;
#pragma unroll
        for (int j = 0; j < 7; ++j) {
            int i = t * 7 + j;
            if (i < NBIN) { bas_out[i] = run; cur_out[i] = run; run += v[j]; }
        }
        if (t == 255) bas_out[NBIN] = run;
    }
}

// ---------- Phase 3: dual scatter (exact compaction both sides) ----------
__global__ __launch_bounds__(256) void scat2_kernel(
    const int* __restrict__ in_map, const int* __restrict__ out_map,
    int* __restrict__ cur_in, int* __restrict__ cur_out,
    unsigned int* __restrict__ binned_in, unsigned char* __restrict__ binned_out)
{
    __shared__ int hi[NBINC];
    __shared__ int ho[NBIN];
    const int t = threadIdx.x;
    const int base = blockIdx.x * BPB;
    for (int c = t; c < NBINC; c += 256) hi[c] = 0;
    for (int c = t; c < NBIN; c += 256) ho[c] = 0;
    __syncthreads();
    for (int i = t; i < BPB; i += 256) {
        int p = base + i;
        if (p < NPAIR) {
            atomicAdd(&hi[(p / MPAIR) * NCHUNK + (in_map[p] >> 10)], 1);
            atomicAdd(&ho[out_map[p] >> 8], 1);
        }
    }
    __syncthreads();
    for (int c = t; c < NBINC; c += 256) {
        int v = hi[c];
        hi[c] = v ? atomicAdd(&cur_in[c], v) : 0;    // abs chunk base
    }
    for (int c = t; c < NBIN; c += 256) {
        int v = ho[c];
        ho[c] = v ? atomicAdd(&cur_out[c], v) : 0;
    }
    __syncthreads();
    for (int i = t; i < BPB; i += 256) {
        int p = base + i;
        if (p >= NPAIR) continue;
        int ir = in_map[p];
        int orow = out_map[p];
        int in_slot = atomicAdd(&hi[(p / MPAIR) * NCHUNK + (ir >> 10)], 1);
        int os      = atomicAdd(&ho[orow >> 8], 1);
        // rl(10b @22..31, unsigned) | os(22b): os < 2.7M < 2^22
        binned_in[in_slot] = ((unsigned int)(ir & 1023) << 22) | (unsigned int)os;
        binned_out[os] = (unsigned char)(orow & 255);
    }
}

// ---------- Phase 4: mv3 — uniform loop + independent-FMA body (R10 pattern) ----------
__global__ __launch_bounds__(256) void mv3_kernel(
    const unsigned short* __restrict__ f16, const float* __restrict__ weight,
    const int* __restrict__ bas_in, const unsigned int* __restrict__ binned_in,
    unsigned short* __restrict__ per_off)
{
    // XCD-swizzled bin mapping: 27 k-bins of one chunk land on one XCD.
    int g = blockIdx.x;
    int k, chunk;
    if (g < 24 * 216) {
        int grp = g / 216, rem = g % 216;
        k = rem >> 3;
        chunk = grp * 8 + (rem & 7);
    } else {
        int tl = g - 24 * 216;
        k = tl >> 2;
        chunk = 192 + (tl & 3);
    }
    k = __builtin_amdgcn_readfirstlane(k);
    chunk = __builtin_amdgcn_readfirstlane(chunk);

    const int key = k * NCHUNK + chunk;
    const int s0 = bas_in[key], s1 = bas_in[key + 1];
    const int nwork = s1 - s0;               // wave-uniform
    const int t = threadIdx.x;

    const float* wk = weight + (size_t)k * (CIN * COUT);

    for (int ib = 0; ib < nwork; ib += 256) {
        const bool act = (ib + t) < nwork;
        const int i = s0 + (act ? ib + t : 0);
        unsigned int e = binned_in[i];
        int rl = (int)(e >> 22);
        int os = (int)(e & 0x3FFFFFu);
        int row = (chunk << 10) + rl;        // 64 KB L2-hot window

        const uint4n* frow = reinterpret_cast<const uint4n*>(f16 + (size_t)row * CIN);
        uint4n q0 = frow[0], q1 = frow[1], q2 = frow[2], q3 = frow[3];  // MLP4

        // full unpack (R10-proven): 32 independent FMAs per ci step, no chains
        float f[CIN];
        f[0] = bf2f_lo(q0.x);  f[1] = bf2f_hi(q0.x);
        f[2] = bf2f_lo(q0.y);  f[3] = bf2f_hi(q0.y);
        f[4] = bf2f_lo(q0.z);  f[5] = bf2f_hi(q0.z);
        f[6] = bf2f_lo(q0.w);  f[7] = bf2f_hi(q0.w);
        f[8] = bf2f_lo(q1.x);  f[9] = bf2f_hi(q1.x);
        f[10] = bf2f_lo(q1.y); f[11] = bf2f_hi(q1.y);
        f[12] = bf2f_lo(q1.z); f[13] = bf2f_hi(q1.z);
        f[14] = bf2f_lo(q1.w); f[15] = bf2f_hi(q1.w);
        f[16] = bf2f_lo(q2.x); f[17] = bf2f_hi(q2.x);
        f[18] = bf2f_lo(q2.y); f[19] = bf2f_hi(q2.y);
        f[20] = bf2f_lo(q2.z); f[21] = bf2f_hi(q2.z);
        f[22] = bf2f_lo(q2.w); f[23] = bf2f_hi(q2.w);
        f[24] = bf2f_lo(q3.x); f[25] = bf2f_hi(q3.x);
        f[26] = bf2f_lo(q3.y); f[27] = bf2f_hi(q3.y);
        f[28] = bf2f_lo(q3.z); f[29] = bf2f_hi(q3.z);
        f[30] = bf2f_lo(q3.w); f[31] = bf2f_hi(q3.w);

        float acc[COUT];
#pragma unroll
        for (int j = 0; j < COUT; ++j) acc[j] = 0.f;
#pragma unroll
        for (int ci = 0; ci < CIN; ++ci) {
            float fv = f[ci];
#pragma unroll
            for (int co = 0; co < COUT; ++co)
                acc[co] = fmaf(fv, wk[ci * COUT + co], acc[co]);
        }

        if (act) {
            uint4n u;
            uint4n* dst = reinterpret_cast<uint4n*>(per_off + (size_t)os * COUT);
#pragma unroll
            for (int j = 0; j < 4; ++j) {
                u.x = bf16pair(acc[8 * j + 0], acc[8 * j + 1]);
                u.y = bf16pair(acc[8 * j + 2], acc[8 * j + 3]);
                u.z = bf16pair(acc[8 * j + 4], acc[8 * j + 5]);
                u.w = bf16pair(acc[8 * j + 6], acc[8 * j + 7]);
                dst[j] = u;                  // random 64B store, L2-merged
            }
        }
    }
}

// ---------- Phase 5: gather4 — contiguous per-bin payload window ----------
__global__ __launch_bounds__(256) void gather4_kernel(
    const unsigned short* __restrict__ per_off,
    const int* __restrict__ bas_out, const unsigned char* __restrict__ binned_out,
    float* __restrict__ out)
{
    __shared__ int sorted[CAPB];             // 12 KB
    __shared__ int cnt[ROWS_PER_BIN];
    __shared__ int scn[ROWS_PER_BIN];
    __shared__ int cur[ROWS_PER_BIN];

    const int b = blockIdx.x;
    const int t = threadIdx.x;
    const int base = bas_out[b];
    const int n = bas_out[b + 1] - base;     // exact count

    const int g = t >> 5, lane = t & 31;

    int c0 = 0;
    do {
        int m = n - c0; if (m > CAPB) m = CAPB; if (m < 0) m = 0;

        cnt[t] = 0;
        __syncthreads();
        for (int i = t; i < m; i += 256)
            atomicAdd(&cnt[binned_out[base + c0 + i]], 1);
        __syncthreads();
        scn[t] = cnt[t];
        __syncthreads();
#pragma unroll
        for (int off = 1; off < 256; off <<= 1) {
            int v = (t >= off) ? scn[t - off] : 0;
            __syncthreads();
            scn[t] += v;
            __syncthreads();
        }
        cur[t] = scn[t] - cnt[t];
        __syncthreads();
        for (int i = t; i < m; i += 256) {
            int rl = binned_out[base + c0 + i];          // L2-hot re-read
            int pos = atomicAdd(&cur[rl], 1);
            sorted[pos] = i;
        }
        __syncthreads();

        // 32-lane group per row; payload reads land in this bin's
        // contiguous [base*64, (base+n)*64) window -> streaming/L2
        for (int r = g; r < ROWS_PER_BIN; r += 8) {
            int grow = (b << 8) + r;
            if (grow >= NOUT) break;
            int s1 = scn[r], s0v = s1 - cnt[r];
            float a0 = 0.f, a1 = 0.f, a2 = 0.f, a3 = 0.f;
            int i = s0v;
            for (; i + 4 <= s1; i += 4) {
                int i0 = base + c0 + sorted[i];
                int i1 = base + c0 + sorted[i + 1];
                int i2 = base + c0 + sorted[i + 2];
                int i3 = base + c0 + sorted[i + 3];
                a0 += bf2f(per_off[(size_t)i0 * COUT + lane]);
                a1 += bf2f(per_off[(size_t)i1 * COUT + lane]);
                a2 += bf2f(per_off[(size_t)i2 * COUT + lane]);
                a3 += bf2f(per_off[(size_t)i3 * COUT + lane]);
            }
            for (; i < s1; ++i)
                a0 += bf2f(per_off[(size_t)(base + c0 + sorted[i]) * COUT + lane]);
            float v = (a0 + a1) + (a2 + a3);
            if (c0 == 0) out[(size_t)grow * COUT + lane] = v;      // also zeros
            else         out[(size_t)grow * COUT + lane] += v;     // ~never
        }
        __syncthreads();
        c0 += CAPB;
    } while (c0 < n);
}

// ---------- last-resort fallback (tiny ws): R1 atomic scatter ----------
__global__ __launch_bounds__(256) void spconvt_fallback(
    const float* __restrict__ feats, const float* __restrict__ weight,
    const int* __restrict__ in_map, const int* __restrict__ out_map,
    float* __restrict__ out)
{
    const int k = blockIdx.y;
    const int m = blockIdx.x * blockDim.x + threadIdx.x;
    const bool active = (m < MPAIR);
    const int mm = active ? m : (MPAIR - 1);
    const int pair = k * MPAIR + mm;
    const int in_row = in_map[pair];
    const int out_row = out_map[pair];
    const float4* frow = reinterpret_cast<const float4*>(feats + (size_t)in_row * CIN);
    float4 f4[8];
#pragma unroll
    for (int i = 0; i < 8; ++i) f4[i] = frow[i];
    const float* f = reinterpret_cast<const float*>(f4);
    float acc[COUT];
#pragma unroll
    for (int i = 0; i < COUT; ++i) acc[i] = 0.f;
    const float* wk = weight + (size_t)k * (CIN * COUT);
#pragma unroll
    for (int ci = 0; ci < CIN; ++ci) {
        const float fv = f[ci];
#pragma unroll
        for (int co = 0; co < COUT; ++co)
            acc[co] = fmaf(fv, wk[ci * COUT + co], acc[co]);
    }
    if (active) {
        float* orow = out + (size_t)out_row * COUT;
#pragma unroll
        for (int co = 0; co < COUT; ++co) atomicAdd(orow + co, acc[co]);
    }
}

extern "C" void kernel_launch(void* const* d_in, const int* in_sizes, int n_in,
                              void* d_out, int out_size, void* d_ws, size_t ws_size,
                              hipStream_t stream) {
    const float* feats  = (const float*)d_in[0];
    const float* weight = (const float*)d_in[1];
    const int* in_map   = (const int*)d_in[2];
    const int* out_map  = (const int*)d_in[3];
    float* out          = (float*)d_out;
    char* ws            = (char*)d_ws;

    if (ws_size >= WS_NEED) {
        int* cnt_in              = (int*)(ws + O_CNTI);
        int* cnt_out             = (int*)(ws + O_CNTO);
        int* bas_in              = (int*)(ws + O_BASI);
        int* bas_out             = (int*)(ws + O_BASO);
        int* cur_in              = (int*)(ws + O_CURI);
        int* cur_out             = (int*)(ws + O_CURO);
        unsigned int* binned_in  = (unsigned int*)(ws + O_BINI);
        unsigned char* binned_out= (unsigned char*)(ws + O_BINO);
        unsigned short* per_off  = (unsigned short*)(ws + O_PEROFF);
        unsigned short* f16      = (unsigned short*)(ws + O_F16);

        (void)hipMemsetAsync(ws, 0, O_BINI, stream);   // all counters

        cvt_kernel<<<dim3((NIN * CIN / 8 + 255) / 256), dim3(256), 0, stream>>>(
            feats, f16);

        hist2_kernel<<<dim3((NPAIR + BPB - 1) / BPB), dim3(256), 0, stream>>>(
            in_map, out_map, cnt_in, cnt_out);
        scan2_kernel<<<dim3(1), dim3(256), 0, stream>>>(
            cnt_in, cnt_out, bas_in, bas_out, cur_in, cur_out);
        scat2_kernel<<<dim3((NPAIR + BPB - 1) / BPB), dim3(256), 0, stream>>>(
            in_map, out_map, cur_in, cur_out, binned_in, binned_out);

        mv3_kernel<<<dim3(NBINC), dim3(256), 0, stream>>>(
            f16, weight, bas_in, binned_in, per_off);

        gather4_kernel<<<dim3(NBIN), dim3(256), 0, stream>>>(
            per_off, bas_out, binned_out, out);
    } else {
        (void)hipMemsetAsync(d_out, 0, (size_t)out_size * sizeof(float), stream);
        spconvt_fallback<<<dim3((MPAIR + 255) / 256, KOFF), dim3(256), 0, stream>>>(
            feats, weight, in_map, out_map, out);
    }
}